// Round 11
// baseline (181.954 us; speedup 1.0000x reference)
//
#include <hip/hip_runtime.h>
#include <math.h>

#define HID 768
#define NB  64
#define HV  384

__device__ __forceinline__ float4 ld4(const float* p) { return *(const float4*)p; }

// ---------------------------------------------------------------------------
// K1: dec1 partial (r0 proven body). H1p[kz][t][n] = sum_{k in chunk kz}
// A0[t][k]*Ws1[k][n], A0 = relu(bits@Ws0+bs0). Grid 192 = 12 n-tiles x 16
// k-chunks of 48.
// ---------------------------------------------------------------------------
__global__ __launch_bounds__(256)
void dec1p_kernel(const float* __restrict__ Ws0, const float* __restrict__ bs0,
                  const float* __restrict__ Ws1, float* __restrict__ H1p) {
    __shared__ float W0s[7 * 48];
    __shared__ float As[48 * 68];
    __shared__ float Bs[48 * 68];
    const int tid = threadIdx.x;
    const int n0 = (blockIdx.x % 12) * 64;
    const int kz = blockIdx.x / 12;
    const int ks = kz * 48;

    for (int e = tid; e < 7 * 48; e += 256) {
        const int r = e / 48, c = e % 48;
        W0s[e] = (r < 6) ? Ws0[(size_t)r * HID + ks + c] : bs0[ks + c];
    }
    for (int e = tid; e < 48 * 16; e += 256) {
        const int k = e >> 4, nq = (e & 15) * 4;
        *(float4*)&Bs[k * 68 + nq] = ld4(Ws1 + (size_t)(ks + k) * HID + n0 + nq);
    }
    __syncthreads();
    for (int e = tid; e < 48 * 64; e += 256) {
        const int k = e >> 6, t = e & 63;
        float v = W0s[6 * 48 + k];
        #pragma unroll
        for (int b = 0; b < 6; ++b)
            v = fmaf((float)((t >> b) & 1), W0s[b * 48 + k], v);
        As[k * 68 + t] = fmaxf(v, 0.f);
    }
    __syncthreads();

    const int tx = tid & 15, ty = tid >> 4;
    float acc[4][4] = {};
    #pragma unroll 8
    for (int kk = 0; kk < 48; ++kk) {
        const float4 a4 = *(const float4*)&As[kk * 68 + ty * 4];
        const float4 b4 = *(const float4*)&Bs[kk * 68 + tx * 4];
        const float av[4] = {a4.x, a4.y, a4.z, a4.w};
        const float bv[4] = {b4.x, b4.y, b4.z, b4.w};
        #pragma unroll
        for (int a = 0; a < 4; ++a)
            #pragma unroll
            for (int b = 0; b < 4; ++b)
                acc[a][b] = fmaf(av[a], bv[b], acc[a][b]);
    }
    #pragma unroll
    for (int a = 0; a < 4; ++a) {
        float4 o = make_float4(acc[a][0], acc[a][1], acc[a][2], acc[a][3]);
        *(float4*)&H1p[((size_t)kz * 64 + ty * 4 + a) * HID + n0 + tx * 4] = o;
    }
}

// ---------------------------------------------------------------------------
// K2: dec2 (measured-good body). pred[t] = argmax(relu(sum_{z<16}
// H1p[z][t]+bs1) @ Ws2 + bs2). 64 blocks x 1 t-row.
// ---------------------------------------------------------------------------
__global__ __launch_bounds__(256)
void dec2_kernel(const float* __restrict__ H1p, const float* __restrict__ bs1,
                 const float* __restrict__ Ws2, const float* __restrict__ bs2,
                 int* __restrict__ pred) {
    __shared__ float sh[HID];
    __shared__ float plp[4][64];
    const int tid = threadIdx.x;
    const int t = blockIdx.x;

    for (int e = tid; e < HID / 4; e += 256) {
        const int k4 = e * 4;
        float4 v = ld4(bs1 + k4);
        #pragma unroll
        for (int z = 0; z < 16; ++z) {
            const float4 p = ld4(H1p + ((size_t)z * 64 + t) * HID + k4);
            v.x += p.x; v.y += p.y; v.z += p.z; v.w += p.w;
        }
        sh[k4 + 0] = fmaxf(v.x, 0.f);
        sh[k4 + 1] = fmaxf(v.y, 0.f);
        sh[k4 + 2] = fmaxf(v.z, 0.f);
        sh[k4 + 3] = fmaxf(v.w, 0.f);
    }
    __syncthreads();
    {
        const int n = tid & 63, part = tid >> 6;
        float p = 0.f;
        #pragma unroll 8
        for (int kk = 0; kk < 192; ++kk) {
            const int k = part * 192 + kk;
            p = fmaf(sh[k], Ws2[k * 64 + n], p);
        }
        plp[part][n] = p;
    }
    __syncthreads();
    if (tid == 0) {
        int best = 0;
        float bv = bs2[0] + plp[0][0] + plp[1][0] + plp[2][0] + plp[3][0];
        for (int n = 1; n < 64; ++n) {
            const float x = bs2[n] + plp[0][n] + plp[1][n] + plp[2][n] + plp[3][n];
            if (x > bv) { bv = x; best = n; }
        }
        pred[t] = best;
    }
}

// ---------------------------------------------------------------------------
// K3: plan (r0 proven body). hdr[0]=P; hdr[1+rank]=s_of_rank;
// hdr[65+s]=rank_of_s (-1 if dead).
// ---------------------------------------------------------------------------
__global__ __launch_bounds__(64)
void plan_kernel(const int* __restrict__ pred, int* __restrict__ hdr) {
    const int lane = threadIdx.x;
    __shared__ int present[64];
    present[lane] = 0;
    __syncthreads();
    present[pred[lane] & 63] = 1;
    __syncthreads();
    const unsigned long long alive = __ballot(present[lane] != 0);
    const int P = __popcll(alive);
    const int rank = __popcll(alive & ((1ull << lane) - 1ull));
    if (lane == 0) hdr[0] = P;
    if (present[lane]) { hdr[1 + rank] = lane; hdr[65 + lane] = rank; }
    else hdr[65 + lane] = -1;
}

// ---------------------------------------------------------------------------
// K4: gemmAB (FUSED gemmA+gemmB). Grid (12 bx, 64 li); li >= P exits.
// Per block: for z=0..5 { stage As/Bs (R8 gemmA formulas, 64x64 tile, 2 kt),
// fresh acc chained over the z-chunk's 128 k (kt-carried) == gemmA partial;
// hs += acc_z in ascending z } == gemmB's v=p0; v+=p1..p5 chain (0+p0==p0).
// Then h2 = relu(hs + bi1) -> Ht in LDS (SA reused) + W2 staged (SB reused)
// -> gemmB's exact 64-kk logits loop -> PLf[bx][li]. Every scalar fmaf
// sequence identical to the split version -> absmax-0 class preserved.
// Eliminates H2p entirely (48.4MB write + 48.4MB read) and one launch.
// LDS 34.8KB. Live blocks 12*P ~ 492 (~1.9/CU) -- risk accepted; read-out
// rule: regression => revert + m-split for 2x blocks.
// ---------------------------------------------------------------------------
__global__ __launch_bounds__(256)
void gemmAB_kernel(const float* __restrict__ Wi0, const float* __restrict__ bi0,
                   const float* __restrict__ Wi1, const float* __restrict__ bi1,
                   const float* __restrict__ Wi2, const int* __restrict__ hdr,
                   float* __restrict__ PLf) {
    __shared__ float SA[64 * 68];   // [k][m], later Ht [n_local][m]
    __shared__ float SB[64 * 68];   // [k][n], later W2 [n_local][o]
    const int tid = threadIdx.x;
    const int P = hdr[0];
    const int li = blockIdx.y;
    if (li >= P) return;
    const int s = hdr[1 + li];
    const int bx = blockIdx.x;      // 0..11
    const int n0 = bx * 64;
    const int tx = tid & 15, ty = tid >> 4;
    const float* arow = Wi0 + (size_t)(64 + s) * HID;
    float hs[4][4] = {};

    for (int z = 0; z < 6; ++z) {
        float acc[4][4] = {};
        for (int kt = 0; kt < 2; ++kt) {
            const int k0 = z * 128 + kt * 64;
            #pragma unroll
            for (int pass = 0; pass < 4; ++pass) {
                const int c = pass * 256 + tid;
                const int m = c >> 4, kq = (c & 15) * 4;
                const float4 a1 = ld4(arow + k0 + kq);
                const float4 a2 = ld4(Wi0 + (size_t)m * HID + k0 + kq);
                const float4 bb = ld4(bi0 + k0 + kq);
                SA[(kq + 0) * 68 + m] = fmaxf(a1.x + a2.x + bb.x, 0.f);
                SA[(kq + 1) * 68 + m] = fmaxf(a1.y + a2.y + bb.y, 0.f);
                SA[(kq + 2) * 68 + m] = fmaxf(a1.z + a2.z + bb.z, 0.f);
                SA[(kq + 3) * 68 + m] = fmaxf(a1.w + a2.w + bb.w, 0.f);
            }
            #pragma unroll
            for (int pass = 0; pass < 4; ++pass) {
                const int c = pass * 256 + tid;
                const int k = c >> 4, nq = (c & 15) * 4;
                *(float4*)&SB[k * 68 + nq] = ld4(Wi1 + (size_t)(k0 + k) * HID + n0 + nq);
            }
            __syncthreads();
            #pragma unroll 8
            for (int kk = 0; kk < 64; ++kk) {
                const float4 a4 = *(const float4*)&SA[kk * 68 + ty * 4];
                const float4 b4 = *(const float4*)&SB[kk * 68 + tx * 4];
                const float av[4] = {a4.x, a4.y, a4.z, a4.w};
                const float bv[4] = {b4.x, b4.y, b4.z, b4.w};
                #pragma unroll
                for (int a = 0; a < 4; ++a)
                    #pragma unroll
                    for (int b = 0; b < 4; ++b)
                        acc[a][b] = fmaf(av[a], bv[b], acc[a][b]);
            }
            __syncthreads();
        }
        #pragma unroll
        for (int a = 0; a < 4; ++a)
            #pragma unroll
            for (int b = 0; b < 4; ++b)
                hs[a][b] += acc[a][b];
    }

    // h2 tile -> Ht[n_local][m] in SA; stage W2 slice into SB.
    {
        const float4 bb = ld4(bi1 + n0 + tx * 4);
        const float bbv[4] = {bb.x, bb.y, bb.z, bb.w};
        #pragma unroll
        for (int a = 0; a < 4; ++a)
            #pragma unroll
            for (int b = 0; b < 4; ++b)
                SA[(tx * 4 + b) * 68 + ty * 4 + a] = fmaxf(hs[a][b] + bbv[b], 0.f);
    }
    #pragma unroll
    for (int pass = 0; pass < 4; ++pass) {
        const int c = pass * 256 + tid;
        const int cl = c >> 4, oq = (c & 15) * 4;
        *(float4*)&SB[cl * 68 + oq] = ld4(Wi2 + (size_t)(n0 + cl) * 64 + oq);
    }
    __syncthreads();

    float pl_[4][4] = {};
    #pragma unroll 16
    for (int kk = 0; kk < 64; ++kk) {
        const float4 a4 = *(const float4*)&SA[kk * 68 + ty * 4];
        const float4 b4 = *(const float4*)&SB[kk * 68 + tx * 4];
        const float av[4] = {a4.x, a4.y, a4.z, a4.w};
        const float bv[4] = {b4.x, b4.y, b4.z, b4.w};
        #pragma unroll
        for (int a = 0; a < 4; ++a)
            #pragma unroll
            for (int b = 0; b < 4; ++b)
                pl_[a][b] = fmaf(av[a], bv[b], pl_[a][b]);
    }
    #pragma unroll
    for (int a = 0; a < 4; ++a) {
        float4 o = make_float4(pl_[a][0], pl_[a][1], pl_[a][2], pl_[a][3]);
        *(float4*)&PLf[((size_t)(bx * 64 + li) * 64 + ty * 4 + a) * 64 + tx * 4] = o;
    }
}

// ---------------------------------------------------------------------------
// K6: reduceA (r0 proven body, hdr). logits = bi2 + sum_{bx<12} PLf[bx][li]
// -> argmax -> j_tab; validity sigmoid. Grid 256; dead s exits.
// ---------------------------------------------------------------------------
__global__ __launch_bounds__(256)
void reduceA_kernel(const float* __restrict__ PLf, const float* __restrict__ bi2,
                    const float* __restrict__ Wv0, const float* __restrict__ bv0,
                    const float* __restrict__ Wv1, const float* __restrict__ bv1,
                    const int* __restrict__ hdr,
                    int* __restrict__ j_tab, float* __restrict__ sig_tab) {
    __shared__ float lg[16 * 68];
    const int tid = threadIdx.x;
    const int s = blockIdx.x >> 2;
    const int li = hdr[65 + s];
    if (li < 0) return;
    const int r0 = blockIdx.x * 16;
    const int rr = tid >> 4, q = tid & 15;
    const int i = (r0 & 63) + rr;
    float4 v = ld4(bi2 + q * 4);
    #pragma unroll
    for (int bx = 0; bx < 12; ++bx) {
        const float4 p = ld4(PLf + ((size_t)(bx * 64 + li) * 64 + i) * 64 + q * 4);
        v.x += p.x; v.y += p.y; v.z += p.z; v.w += p.w;
    }
    *(float4*)&lg[rr * 68 + q * 4] = v;
    __syncthreads();
    if (tid < 16) {
        int best = 0; float bv = lg[tid * 68];
        for (int n = 1; n < 64; ++n) {
            const float x = lg[tid * 68 + n];
            if (x > bv) { bv = x; best = n; }
        }
        j_tab[r0 + tid] = best;
    }
    {
        const int r = r0 + rr;
        const int ii = r & 63;
        const float* w1 = Wv0 + (size_t)(64 + s) * HV;
        const float* w2 = Wv0 + (size_t)ii * HV;
        float sum = 0.f;
        #pragma unroll 4
        for (int c = q; c < HV; c += 16) {
            const float hv = fmaxf(w1[c] + w2[c] + bv0[c], 0.f);
            sum = fmaf(hv, Wv1[c], sum);
        }
        #pragma unroll
        for (int m = 8; m >= 1; m >>= 1) sum += __shfl_xor(sum, m);
        if (q == 0) sig_tab[r] = 1.f / (1.f + expf(-(sum + bv1[0])));
    }
}

// ---------------------------------------------------------------------------
// K7: output. out[b,i] = a_bits[b, j_tab[pred[t_b]*64+i]] * sig_tab[...]
// ---------------------------------------------------------------------------
__global__ __launch_bounds__(256)
void output_kernel(const float* __restrict__ a_bits, const int* __restrict__ shift_amount,
                   const int* __restrict__ pred, const int* __restrict__ j_tab,
                   const float* __restrict__ sig_tab, float* __restrict__ out, int B) {
    const int tid = threadIdx.x;
    const int i = tid & 63;
    const int b = blockIdx.x * 4 + (tid >> 6);
    if (b >= B) return;
    const int t = shift_amount[b] & 63;
    const int s = pred[t];
    const int idx = s * 64 + i;
    const int j = j_tab[idx];
    out[(size_t)b * 64 + i] = a_bits[(size_t)b * 64 + j] * sig_tab[idx];
}

// ---------------------------------------------------------------------------
extern "C" void kernel_launch(void* const* d_in, const int* in_sizes, int n_in,
                              void* d_out, int out_size, void* d_ws, size_t ws_size,
                              hipStream_t stream) {
    const float* a_bits       = (const float*)d_in[0];
    const int*   shift_amount = (const int*)d_in[1];
    const float* Ws0 = (const float*)d_in[2];
    const float* bs0 = (const float*)d_in[3];
    const float* Ws1 = (const float*)d_in[4];
    const float* bs1 = (const float*)d_in[5];
    const float* Ws2 = (const float*)d_in[6];
    const float* bs2 = (const float*)d_in[7];
    const float* Wi0 = (const float*)d_in[8];
    const float* bi0 = (const float*)d_in[9];
    const float* Wi1 = (const float*)d_in[10];
    const float* bi1 = (const float*)d_in[11];
    const float* Wi2 = (const float*)d_in[12];
    const float* bi2 = (const float*)d_in[13];
    const float* Wv0 = (const float*)d_in[14];
    const float* bv0 = (const float*)d_in[15];
    const float* Wv1 = (const float*)d_in[16];
    const float* bv1 = (const float*)d_in[17];
    float* out = (float*)d_out;
    const int B = in_sizes[1];

    char* ws = (char*)d_ws;
    int*   pred    = (int*)ws;                  // 64 ints
    int*   j_tab   = (int*)(ws + 1024);         // 4096 ints
    float* sig_tab = (float*)(ws + 20480);      // 4096 floats
    int*   hdr     = (int*)(ws + 40960);        // P + s_of_rank[64] + rank_of_s[64]
    // Aliased region at +65536 (stream-ordered reuse):
    //   H1p (dec1p->dec2): 16*64*768*4 = 3.1 MB
    float* H1p = (float*)(ws + 65536);
    float* PLf = (float*)(ws + 65536 + 75497472); // 12*64*64*64*4 = 12.6 MB (offset kept stable)

    dec1p_kernel<<<192, 256, 0, stream>>>(Ws0, bs0, Ws1, H1p);
    dec2_kernel<<<64, 256, 0, stream>>>(H1p, bs1, Ws2, bs2, pred);
    plan_kernel<<<1, 64, 0, stream>>>(pred, hdr);
    gemmAB_kernel<<<dim3(12, 64), 256, 0, stream>>>(Wi0, bi0, Wi1, bi1, Wi2, hdr, PLf);
    reduceA_kernel<<<256, 256, 0, stream>>>(PLf, bi2, Wv0, bv0, Wv1, bv1, hdr,
                                            j_tab, sig_tab);
    output_kernel<<<(B + 3) / 4, 256, 0, stream>>>(a_bits, shift_amount, pred,
                                                   j_tab, sig_tab, out, B);
}

// Round 14
// 153.855 us; speedup vs baseline: 1.1826x; 1.1826x over previous
//
#include <hip/hip_runtime.h>
#include <math.h>

#define HID 768
#define NB  64
#define HV  384

__device__ __forceinline__ float4 ld4(const float* p) { return *(const float4*)p; }

// ---------------------------------------------------------------------------
// K1: dec1 partial. EXPERIMENT: n-tile 32 (was 64) -> grid 384 = 24 n-tiles
// x 16 k-chunks of 48 (1.5 blocks/CU, was 0.75). Per-output 48-step
// ascending-k fmaf chain identical to r0 -> H1p bit-identical. Frag 2x4
// (tx&7 n-quads, ty>>3 m-pairs); Bs pad 36 (144B rows, float4-aligned).
// ---------------------------------------------------------------------------
__global__ __launch_bounds__(256)
void dec1p_kernel(const float* __restrict__ Ws0, const float* __restrict__ bs0,
                  const float* __restrict__ Ws1, float* __restrict__ H1p) {
    __shared__ float W0s[7 * 48];
    __shared__ float As[48 * 68];
    __shared__ float Bs[48 * 36];
    const int tid = threadIdx.x;
    const int n0 = (blockIdx.x % 24) * 32;
    const int kz = blockIdx.x / 24;
    const int ks = kz * 48;

    for (int e = tid; e < 7 * 48; e += 256) {
        const int r = e / 48, c = e % 48;
        W0s[e] = (r < 6) ? Ws0[(size_t)r * HID + ks + c] : bs0[ks + c];
    }
    for (int e = tid; e < 48 * 8; e += 256) {
        const int k = e >> 3, nq = (e & 7) * 4;
        *(float4*)&Bs[k * 36 + nq] = ld4(Ws1 + (size_t)(ks + k) * HID + n0 + nq);
    }
    __syncthreads();
    for (int e = tid; e < 48 * 64; e += 256) {
        const int k = e >> 6, t = e & 63;
        float v = W0s[6 * 48 + k];
        #pragma unroll
        for (int b = 0; b < 6; ++b)
            v = fmaf((float)((t >> b) & 1), W0s[b * 48 + k], v);
        As[k * 68 + t] = fmaxf(v, 0.f);
    }
    __syncthreads();

    const int tx = tid & 7, ty = tid >> 3;   // tx: 8 n-quads, ty: 32 m-pairs
    float acc[2][4] = {};
    #pragma unroll 8
    for (int kk = 0; kk < 48; ++kk) {
        const float2 a2 = *(const float2*)&As[kk * 68 + ty * 2];
        const float4 b4 = *(const float4*)&Bs[kk * 36 + tx * 4];
        const float av[2] = {a2.x, a2.y};
        const float bv[4] = {b4.x, b4.y, b4.z, b4.w};
        #pragma unroll
        for (int a = 0; a < 2; ++a)
            #pragma unroll
            for (int b = 0; b < 4; ++b)
                acc[a][b] = fmaf(av[a], bv[b], acc[a][b]);
    }
    #pragma unroll
    for (int a = 0; a < 2; ++a) {
        float4 o = make_float4(acc[a][0], acc[a][1], acc[a][2], acc[a][3]);
        *(float4*)&H1p[((size_t)kz * 64 + ty * 2 + a) * HID + n0 + tx * 4] = o;
    }
}

// ---------------------------------------------------------------------------
// K2: dec2 (measured-good body). pred[t] = argmax(relu(sum_{z<16}
// H1p[z][t]+bs1) @ Ws2 + bs2). 64 blocks x 1 t-row.
// ---------------------------------------------------------------------------
__global__ __launch_bounds__(256)
void dec2_kernel(const float* __restrict__ H1p, const float* __restrict__ bs1,
                 const float* __restrict__ Ws2, const float* __restrict__ bs2,
                 int* __restrict__ pred) {
    __shared__ float sh[HID];
    __shared__ float plp[4][64];
    const int tid = threadIdx.x;
    const int t = blockIdx.x;

    for (int e = tid; e < HID / 4; e += 256) {
        const int k4 = e * 4;
        float4 v = ld4(bs1 + k4);
        #pragma unroll
        for (int z = 0; z < 16; ++z) {
            const float4 p = ld4(H1p + ((size_t)z * 64 + t) * HID + k4);
            v.x += p.x; v.y += p.y; v.z += p.z; v.w += p.w;
        }
        sh[k4 + 0] = fmaxf(v.x, 0.f);
        sh[k4 + 1] = fmaxf(v.y, 0.f);
        sh[k4 + 2] = fmaxf(v.z, 0.f);
        sh[k4 + 3] = fmaxf(v.w, 0.f);
    }
    __syncthreads();
    {
        const int n = tid & 63, part = tid >> 6;
        float p = 0.f;
        #pragma unroll 8
        for (int kk = 0; kk < 192; ++kk) {
            const int k = part * 192 + kk;
            p = fmaf(sh[k], Ws2[k * 64 + n], p);
        }
        plp[part][n] = p;
    }
    __syncthreads();
    if (tid == 0) {
        int best = 0;
        float bv = bs2[0] + plp[0][0] + plp[1][0] + plp[2][0] + plp[3][0];
        for (int n = 1; n < 64; ++n) {
            const float x = bs2[n] + plp[0][n] + plp[1][n] + plp[2][n] + plp[3][n];
            if (x > bv) { bv = x; best = n; }
        }
        pred[t] = best;
    }
}

// ---------------------------------------------------------------------------
// K3: plan (r0 proven body). hdr[0]=P; hdr[1+rank]=s_of_rank;
// hdr[65+s]=rank_of_s (-1 if dead).
// ---------------------------------------------------------------------------
__global__ __launch_bounds__(64)
void plan_kernel(const int* __restrict__ pred, int* __restrict__ hdr) {
    const int lane = threadIdx.x;
    __shared__ int present[64];
    present[lane] = 0;
    __syncthreads();
    present[pred[lane] & 63] = 1;
    __syncthreads();
    const unsigned long long alive = __ballot(present[lane] != 0);
    const int P = __popcll(alive);
    const int rank = __popcll(alive & ((1ull << lane) - 1ull));
    if (lane == 0) hdr[0] = P;
    if (present[lane]) { hdr[1 + rank] = lane; hdr[65 + lane] = rank; }
    else hdr[65 + lane] = -1;
}

// ---------------------------------------------------------------------------
// K4: gemmA (R8 proven body, measured in 154.8 total). 64m x 64n tile, 4x4
// frag, BK=64, grid (12 n-tiles, 64 rank slots, 6 z). REVERT of the R11
// fusion (gemmAB measured 57.5us at 6.1% occupancy - latency-bound).
// ---------------------------------------------------------------------------
__global__ __launch_bounds__(256)
void gemmA_kernel(const float* __restrict__ Wi0, const float* __restrict__ bi0,
                  const float* __restrict__ Wi1, const int* __restrict__ hdr,
                  float* __restrict__ H2p) {
    __shared__ float As[64 * 68];   // [k][m] 17.4 KB
    __shared__ float Bs[64 * 68];   // [k][n] 17.4 KB
    const int tid = threadIdx.x;
    const int P = hdr[0];
    const int li = blockIdx.y;
    if (li >= P) return;
    const int s = hdr[1 + li];
    const int n0 = blockIdx.x * 64;
    const int z = blockIdx.z;
    const int tx = tid & 15, ty = tid >> 4;
    const float* arow = Wi0 + (size_t)(64 + s) * HID;
    float acc[4][4] = {};

    for (int kt = 0; kt < 2; ++kt) {
        const int k0 = z * 128 + kt * 64;
        #pragma unroll
        for (int pass = 0; pass < 4; ++pass) {
            const int c = pass * 256 + tid;
            const int m = c >> 4, kq = (c & 15) * 4;
            const float4 a1 = ld4(arow + k0 + kq);
            const float4 a2 = ld4(Wi0 + (size_t)m * HID + k0 + kq);
            const float4 bb = ld4(bi0 + k0 + kq);
            As[(kq + 0) * 68 + m] = fmaxf(a1.x + a2.x + bb.x, 0.f);
            As[(kq + 1) * 68 + m] = fmaxf(a1.y + a2.y + bb.y, 0.f);
            As[(kq + 2) * 68 + m] = fmaxf(a1.z + a2.z + bb.z, 0.f);
            As[(kq + 3) * 68 + m] = fmaxf(a1.w + a2.w + bb.w, 0.f);
        }
        #pragma unroll
        for (int pass = 0; pass < 4; ++pass) {
            const int c = pass * 256 + tid;
            const int k = c >> 4, nq = (c & 15) * 4;
            *(float4*)&Bs[k * 68 + nq] = ld4(Wi1 + (size_t)(k0 + k) * HID + n0 + nq);
        }
        __syncthreads();
        #pragma unroll 8
        for (int kk = 0; kk < 64; ++kk) {
            const float4 a4 = *(const float4*)&As[kk * 68 + ty * 4];
            const float4 b4 = *(const float4*)&Bs[kk * 68 + tx * 4];
            const float av[4] = {a4.x, a4.y, a4.z, a4.w};
            const float bv[4] = {b4.x, b4.y, b4.z, b4.w};
            #pragma unroll
            for (int a = 0; a < 4; ++a)
                #pragma unroll
                for (int b = 0; b < 4; ++b)
                    acc[a][b] = fmaf(av[a], bv[b], acc[a][b]);
        }
        __syncthreads();
    }
    float* dst = H2p + ((size_t)(z * 64 + li) * 64) * HID + n0;
    #pragma unroll
    for (int a = 0; a < 4; ++a) {
        float4 o = make_float4(acc[a][0], acc[a][1], acc[a][2], acc[a][3]);
        *(float4*)(dst + (size_t)(ty * 4 + a) * HID + tx * 4) = o;
    }
}

// ---------------------------------------------------------------------------
// K5: gemmB (r0 proven body, hdr). Grid (12 n-slices of 64, 64 rank slots).
// h2 = relu(sum_{z<6 ascending} + bi1); partial logits vs Wi2 slice -> PLf.
// ---------------------------------------------------------------------------
__global__ __launch_bounds__(256)
void gemmB_kernel(const float* __restrict__ bi1, const float* __restrict__ Wi2,
                  const int* __restrict__ hdr, const float* __restrict__ H2p,
                  float* __restrict__ PLf) {
    __shared__ float Ht[64 * 68];   // [n_local][m]
    __shared__ float W2[64 * 68];   // [n_local][o]
    const int tid = threadIdx.x;
    const int P = hdr[0];
    const int li = blockIdx.y;
    if (li >= P) return;
    const int bx = blockIdx.x;      // 0..11
    const int n0 = bx * 64;
    const size_t zstep = (size_t)64 * 64 * HID;

    for (int e = tid; e < 1024; e += 256) {
        const int m = e >> 4, nq = (e & 15) * 4;
        const float* base = H2p + ((size_t)li * 64 + m) * HID + n0 + nq;
        float4 v = ld4(base);
        #pragma unroll
        for (int z = 1; z < 6; ++z) {
            const float4 p = ld4(base + z * zstep);
            v.x += p.x; v.y += p.y; v.z += p.z; v.w += p.w;
        }
        const float4 bb = ld4(bi1 + n0 + nq);
        Ht[(nq + 0) * 68 + m] = fmaxf(v.x + bb.x, 0.f);
        Ht[(nq + 1) * 68 + m] = fmaxf(v.y + bb.y, 0.f);
        Ht[(nq + 2) * 68 + m] = fmaxf(v.z + bb.z, 0.f);
        Ht[(nq + 3) * 68 + m] = fmaxf(v.w + bb.w, 0.f);
    }
    #pragma unroll
    for (int pass = 0; pass < 4; ++pass) {
        const int c = pass * 256 + tid;
        const int cl = c >> 4, oq = (c & 15) * 4;
        *(float4*)&W2[cl * 68 + oq] = ld4(Wi2 + (size_t)(n0 + cl) * 64 + oq);
    }
    __syncthreads();
    const int tx = tid & 15, ty = tid >> 4;
    float pl_[4][4] = {};
    #pragma unroll 16
    for (int kk = 0; kk < 64; ++kk) {
        const float4 a4 = *(const float4*)&Ht[kk * 68 + ty * 4];
        const float4 b4 = *(const float4*)&W2[kk * 68 + tx * 4];
        const float av[4] = {a4.x, a4.y, a4.z, a4.w};
        const float bv[4] = {b4.x, b4.y, b4.z, b4.w};
        #pragma unroll
        for (int a = 0; a < 4; ++a)
            #pragma unroll
            for (int b = 0; b < 4; ++b)
                pl_[a][b] = fmaf(av[a], bv[b], pl_[a][b]);
    }
    #pragma unroll
    for (int a = 0; a < 4; ++a) {
        float4 o = make_float4(pl_[a][0], pl_[a][1], pl_[a][2], pl_[a][3]);
        *(float4*)&PLf[((size_t)(bx * 64 + li) * 64 + ty * 4 + a) * 64 + tx * 4] = o;
    }
}

// ---------------------------------------------------------------------------
// K6: reduceA (r0 proven body, hdr). logits = bi2 + sum_{bx<12} PLf[bx][li]
// -> argmax -> j_tab; validity sigmoid. Grid 256; dead s exits.
// ---------------------------------------------------------------------------
__global__ __launch_bounds__(256)
void reduceA_kernel(const float* __restrict__ PLf, const float* __restrict__ bi2,
                    const float* __restrict__ Wv0, const float* __restrict__ bv0,
                    const float* __restrict__ Wv1, const float* __restrict__ bv1,
                    const int* __restrict__ hdr,
                    int* __restrict__ j_tab, float* __restrict__ sig_tab) {
    __shared__ float lg[16 * 68];
    const int tid = threadIdx.x;
    const int s = blockIdx.x >> 2;
    const int li = hdr[65 + s];
    if (li < 0) return;
    const int r0 = blockIdx.x * 16;
    const int rr = tid >> 4, q = tid & 15;
    const int i = (r0 & 63) + rr;
    float4 v = ld4(bi2 + q * 4);
    #pragma unroll
    for (int bx = 0; bx < 12; ++bx) {
        const float4 p = ld4(PLf + ((size_t)(bx * 64 + li) * 64 + i) * 64 + q * 4);
        v.x += p.x; v.y += p.y; v.z += p.z; v.w += p.w;
    }
    *(float4*)&lg[rr * 68 + q * 4] = v;
    __syncthreads();
    if (tid < 16) {
        int best = 0; float bv = lg[tid * 68];
        for (int n = 1; n < 64; ++n) {
            const float x = lg[tid * 68 + n];
            if (x > bv) { bv = x; best = n; }
        }
        j_tab[r0 + tid] = best;
    }
    {
        const int r = r0 + rr;
        const int ii = r & 63;
        const float* w1 = Wv0 + (size_t)(64 + s) * HV;
        const float* w2 = Wv0 + (size_t)ii * HV;
        float sum = 0.f;
        #pragma unroll 4
        for (int c = q; c < HV; c += 16) {
            const float hv = fmaxf(w1[c] + w2[c] + bv0[c], 0.f);
            sum = fmaf(hv, Wv1[c], sum);
        }
        #pragma unroll
        for (int m = 8; m >= 1; m >>= 1) sum += __shfl_xor(sum, m);
        if (q == 0) sig_tab[r] = 1.f / (1.f + expf(-(sum + bv1[0])));
    }
}

// ---------------------------------------------------------------------------
// K7: output. out[b,i] = a_bits[b, j_tab[pred[t_b]*64+i]] * sig_tab[...]
// ---------------------------------------------------------------------------
__global__ __launch_bounds__(256)
void output_kernel(const float* __restrict__ a_bits, const int* __restrict__ shift_amount,
                   const int* __restrict__ pred, const int* __restrict__ j_tab,
                   const float* __restrict__ sig_tab, float* __restrict__ out, int B) {
    const int tid = threadIdx.x;
    const int i = tid & 63;
    const int b = blockIdx.x * 4 + (tid >> 6);
    if (b >= B) return;
    const int t = shift_amount[b] & 63;
    const int s = pred[t];
    const int idx = s * 64 + i;
    const int j = j_tab[idx];
    out[(size_t)b * 64 + i] = a_bits[(size_t)b * 64 + j] * sig_tab[idx];
}

// ---------------------------------------------------------------------------
extern "C" void kernel_launch(void* const* d_in, const int* in_sizes, int n_in,
                              void* d_out, int out_size, void* d_ws, size_t ws_size,
                              hipStream_t stream) {
    const float* a_bits       = (const float*)d_in[0];
    const int*   shift_amount = (const int*)d_in[1];
    const float* Ws0 = (const float*)d_in[2];
    const float* bs0 = (const float*)d_in[3];
    const float* Ws1 = (const float*)d_in[4];
    const float* bs1 = (const float*)d_in[5];
    const float* Ws2 = (const float*)d_in[6];
    const float* bs2 = (const float*)d_in[7];
    const float* Wi0 = (const float*)d_in[8];
    const float* bi0 = (const float*)d_in[9];
    const float* Wi1 = (const float*)d_in[10];
    const float* bi1 = (const float*)d_in[11];
    const float* Wi2 = (const float*)d_in[12];
    const float* bi2 = (const float*)d_in[13];
    const float* Wv0 = (const float*)d_in[14];
    const float* bv0 = (const float*)d_in[15];
    const float* Wv1 = (const float*)d_in[16];
    const float* bv1 = (const float*)d_in[17];
    float* out = (float*)d_out;
    const int B = in_sizes[1];

    char* ws = (char*)d_ws;
    int*   pred    = (int*)ws;                  // 64 ints
    int*   j_tab   = (int*)(ws + 1024);         // 4096 ints
    float* sig_tab = (float*)(ws + 20480);      // 4096 floats
    int*   hdr     = (int*)(ws + 40960);        // P + s_of_rank[64] + rank_of_s[64]
    // Aliased region at +65536 (stream-ordered reuse):
    //   H1p (dec1p->dec2): 16*64*768*4 = 3.1 MB
    //   H2p (gemmA->gemmB): 6*64*64*768*4 = 75,497,472 B
    float* H1p = (float*)(ws + 65536);
    float* H2p = (float*)(ws + 65536);
    float* PLf = (float*)(ws + 65536 + 75497472); // 12*64*64*64*4 = 12.6 MB

    dec1p_kernel<<<384, 256, 0, stream>>>(Ws0, bs0, Ws1, H1p);
    dec2_kernel<<<64, 256, 0, stream>>>(H1p, bs1, Ws2, bs2, pred);
    plan_kernel<<<1, 64, 0, stream>>>(pred, hdr);
    gemmA_kernel<<<dim3(12, 64, 6), 256, 0, stream>>>(Wi0, bi0, Wi1, hdr, H2p);
    gemmB_kernel<<<dim3(12, 64), 256, 0, stream>>>(bi1, Wi2, hdr, H2p, PLf);
    reduceA_kernel<<<256, 256, 0, stream>>>(PLf, bi2, Wv0, bv0, Wv1, bv1, hdr,
                                            j_tab, sig_tab);
    output_kernel<<<(B + 3) / 4, 256, 0, stream>>>(a_bits, shift_amount, pred,
                                                   j_tab, sig_tab, out, B);
}